// Round 9
// baseline (200.038 us; speedup 1.0000x reference)
//
#include <hip/hip_runtime.h>
#include <hip/hip_bf16.h>
#include <math.h>

#define BB    8
#define NN    512
#define DD    768
#define DEPD  64

typedef __attribute__((ext_vector_type(4))) float f32x4;
typedef __attribute__((ext_vector_type(8))) short bf16x8;

__device__ __forceinline__ unsigned short to_bf16(float x) {
    __hip_bfloat16 h = __float2bfloat16(x);       // RNE
    return __builtin_bit_cast(unsigned short, h);
}

// ---------------- kernel 1: s_nbr[b,j] = f·w_nbr, s_asp[b,j] = f·w_asp ----
__global__ __launch_bounds__(256) void k_proj(const float* __restrict__ feat,
                                              const float* __restrict__ watt,
                                              float* __restrict__ snbr,
                                              float* __restrict__ sasp)
{
    int flat = blockIdx.x * 4 + (threadIdx.x >> 6);   // b*N + j
    int lane = threadIdx.x & 63;
    const float* frow = feat + (size_t)flat * DD + lane * 4;
    const float* wn   = watt + lane * 4;              // w_nbr = w[:768]
    const float* wa   = watt + DD + DEPD + lane * 4;  // w_asp = w[832:1600]
    float accn = 0.f, acca = 0.f;
#pragma unroll
    for (int k = 0; k < 3; ++k) {
        float4 f = *(const float4*)(frow + k * 256);
        float4 n = *(const float4*)(wn + k * 256);
        float4 a = *(const float4*)(wa + k * 256);
        accn += f.x*n.x + f.y*n.y + f.z*n.z + f.w*n.w;
        acca += f.x*a.x + f.y*a.y + f.z*a.z + f.w*a.w;
    }
#pragma unroll
    for (int off = 1; off < 64; off <<= 1) {
        accn += __shfl_xor(accn, off);
        acca += __shfl_xor(acca, off);
    }
    if (lane == 0) { snbr[flat] = accn; sasp[flat] = acca; }
}

// ---------------- kernel 1b: featT[b][d][j] = bf16(feat[b][j][d]) ---------
__global__ __launch_bounds__(256) void k_cast(const float* __restrict__ feat,
                                              unsigned short* __restrict__ featT)
{
    int b  = blockIdx.z;
    int j0 = blockIdx.y * 64;
    int d0 = blockIdx.x * 64;
    int t  = threadIdx.x;

    __shared__ unsigned short lt[64][65];

    int dd = t & 63, j4 = t >> 6;
#pragma unroll
    for (int it = 0; it < 16; ++it) {
        int jj = j4 * 16 + it;
        float v = feat[((size_t)(b * NN) + (j0 + jj)) * DD + d0 + dd];
        lt[dd][jj] = to_bf16(v);
    }
    __syncthreads();

    int jj2 = t & 63, d4 = t >> 6;
#pragma unroll
    for (int it = 0; it < 16; ++it) {
        int dd2 = d4 * 16 + it;
        featT[((size_t)(b * DD) + (d0 + dd2)) * NN + j0 + jj2] = lt[dd2][jj2];
    }
}

// ---------------- kernel 2: sdep + masked softmax -> bf16 weights ---------
// Phase 1 restructured: each THREAD owns full j-rows (j=tid, j=tid+256).
// 16 independent float4 loads per row, 4 parallel FMA chains, nz via
// max|a| (FP compare semantics: -0.0 counts as zero, matching any(a!=0)).
// Zero shuffles / LDS ops / divergence in the 537MB streaming loop.
// Phase 2 (block softmax) verbatim from R6-R8.
__global__ __launch_bounds__(256) void k_score(const float* __restrict__ adj,
                                               const float* __restrict__ snbr,
                                               const float* __restrict__ sasp,
                                               const int* __restrict__ aspect,
                                               const float* __restrict__ watt,
                                               unsigned short* __restrict__ wtsB,
                                               int* __restrict__ upd)
{
    int bi  = blockIdx.x;          // b*N + i
    int b   = bi >> 9;
    int tid = threadIdx.x;

    __shared__ float sdep[NN];     // -INF = masked
    __shared__ float sred[4];

    // w_dep: uniform constant-offset loads -> SGPRs
    float wdep[DEPD];
#pragma unroll
    for (int k = 0; k < DEPD; ++k) wdep[k] = watt[DD + k];

    const float* arow = adj + (size_t)bi * NN * DEPD;
#pragma unroll
    for (int jj = 0; jj < 2; ++jj) {
        int j = tid + jj * 256;
        const float* ap = arow + (size_t)j * DEPD;
        float a0 = 0.f, a1 = 0.f, a2 = 0.f, a3 = 0.f;   // 4 parallel chains
        float mab = 0.f;
#pragma unroll
        for (int k = 0; k < 16; ++k) {
            float4 a = *(const float4*)(ap + k * 4);
            a0 = fmaf(a.x, wdep[4*k + 0], a0);
            a1 = fmaf(a.y, wdep[4*k + 1], a1);
            a2 = fmaf(a.z, wdep[4*k + 2], a2);
            a3 = fmaf(a.w, wdep[4*k + 3], a3);
            mab = fmaxf(mab, fmaxf(fmaxf(fabsf(a.x), fabsf(a.y)),
                                   fmaxf(fabsf(a.z), fabsf(a.w))));
        }
        float sum = (a0 + a1) + (a2 + a3);
        sdep[j] = (mab > 0.f) ? sum : -INFINITY;
    }
    __syncthreads();

    float sa = sasp[bi];
    int j0 = tid, j1 = tid + 256;
    float d0 = sdep[j0], d1 = sdep[j1];
    float sc0 = d0 + snbr[(b << 9) + j0] + sa;   // -INF stays -INF
    float sc1 = d1 + snbr[(b << 9) + j1] + sa;

    float v = fmaxf(sc0, sc1);
#pragma unroll
    for (int off = 1; off < 64; off <<= 1) v = fmaxf(v, __shfl_xor(v, off));
    if ((tid & 63) == 0) sred[tid >> 6] = v;
    __syncthreads();
    float mx = fmaxf(fmaxf(sred[0], sred[1]), fmaxf(sred[2], sred[3]));
    __syncthreads();

    float e0 = d0 > -1e37f ? __expf(sc0 - mx) : 0.f;
    float e1 = d1 > -1e37f ? __expf(sc1 - mx) : 0.f;
    v = e0 + e1;
#pragma unroll
    for (int off = 1; off < 64; off <<= 1) v += __shfl_xor(v, off);
    if ((tid & 63) == 0) sred[tid >> 6] = v;
    __syncthreads();
    float sm = sred[0] + sred[1] + sred[2] + sred[3];

    float inv = sm > 0.f ? 1.f / sm : 0.f;
    size_t wb = (size_t)bi * NN;
    wtsB[wb + j0] = to_bf16(e0 * inv);     // coalesced 2B stores
    wtsB[wb + j1] = to_bf16(e1 * inv);
    if (tid == 0) upd[bi] = (aspect[bi] != 0) && (mx > -1e37f);
}

// ---------------- kernel 3: MFMA agg, XCD-pinned by batch ------------------
// (verbatim R8)
__global__ __launch_bounds__(256) void k_agg(const unsigned short* __restrict__ wtsB,
                                             const unsigned short* __restrict__ featT,
                                             const float* __restrict__ feat,
                                             const int* __restrict__ upd,
                                             float* __restrict__ out)
{
    int blk  = blockIdx.x;
    int b    = blk & 7;            // XCD pin
    int rem  = blk >> 3;           // 0..383
    int dblk = rem % 24;
    int iblk = rem / 24;           // 0..15

    int wave = threadIdx.x >> 6;
    int l    = threadIdx.x & 63;
    int i0   = iblk * 32 + (wave >> 1) * 16;
    int d0   = dblk * 32 + (wave & 1) * 16;
    int lr   = l & 15, lg = l >> 4;

    const unsigned short* wrow = wtsB  + ((size_t)(b * NN + i0 + lr)) * NN + lg * 8;
    const unsigned short* frow = featT + ((size_t)(b * DD + d0 + lr)) * NN + lg * 8;

    f32x4 acc = {0.f, 0.f, 0.f, 0.f};
#pragma unroll
    for (int k = 0; k < NN; k += 32) {
        bf16x8 av = *(const bf16x8*)(wrow + k);
        bf16x8 bv = *(const bf16x8*)(frow + k);
        acc = __builtin_amdgcn_mfma_f32_16x16x32_bf16(av, bv, acc, 0, 0, 0);
    }

    int dcol = d0 + lr;
#pragma unroll
    for (int reg = 0; reg < 4; ++reg) {
        int ii   = i0 + lg * 4 + reg;
        int rowi = b * NN + ii;
        float o  = upd[rowi] ? acc[reg] : feat[(size_t)rowi * DD + dcol];
        out[(size_t)rowi * DD + dcol] = o;
    }
}

extern "C" void kernel_launch(void* const* d_in, const int* in_sizes, int n_in,
                              void* d_out, int out_size, void* d_ws, size_t ws_size,
                              hipStream_t stream)
{
    (void)in_sizes; (void)n_in; (void)out_size; (void)ws_size;
    const float* feat = (const float*)d_in[0];
    const int*   asp  = (const int*)d_in[1];
    const float* adj  = (const float*)d_in[2];
    const float* watt = (const float*)d_in[3];
    float* out = (float*)d_out;

    // workspace: wtsB bf16 [8][512][512] (4MB) | featT bf16 [8][768][512]
    // (6.3MB) | snbr | sasp | upd
    unsigned short* wtsB  = (unsigned short*)d_ws;
    unsigned short* featT = wtsB + (size_t)BB * NN * NN;
    float* snbr = (float*)(featT + (size_t)BB * DD * NN);
    float* sasp = snbr + BB * NN;
    int*   upd  = (int*)(sasp + BB * NN);

    k_proj<<<BB * NN / 4, 256, 0, stream>>>(feat, watt, snbr, sasp);
    dim3 gc(DD / 64, NN / 64, BB);
    k_cast<<<gc, 256, 0, stream>>>(feat, featT);
    k_score<<<BB * NN, 256, 0, stream>>>(adj, snbr, sasp, asp, watt, wtsB, upd);
    k_agg<<<BB * (NN / 32) * (DD / 32), 256, 0, stream>>>(wtsB, featT, feat, upd, out);
}

// Round 10
// 162.334 us; speedup vs baseline: 1.2323x; 1.2323x over previous
//
#include <hip/hip_runtime.h>
#include <hip/hip_bf16.h>
#include <math.h>

#define BB    8
#define NN    512
#define DD    768
#define DEPD  64

typedef __attribute__((ext_vector_type(4))) float f32x4;
typedef __attribute__((ext_vector_type(8))) short bf16x8;

__device__ __forceinline__ unsigned short to_bf16(float x) {
    __hip_bfloat16 h = __float2bfloat16(x);       // RNE
    return __builtin_bit_cast(unsigned short, h);
}

// 16-lane-row sum via DPP (VALU pipe only, no LDS):
// quad_perm[1,0,3,2] -> quad_perm[2,3,0,1] -> row_half_mirror -> row_mirror
__device__ __forceinline__ float dpp_sum16(float x) {
    int t;
    t = __builtin_amdgcn_update_dpp(0, __float_as_int(x), 0xB1, 0xF, 0xF, true);
    x += __int_as_float(t);
    t = __builtin_amdgcn_update_dpp(0, __float_as_int(x), 0x4E, 0xF, 0xF, true);
    x += __int_as_float(t);
    t = __builtin_amdgcn_update_dpp(0, __float_as_int(x), 0x141, 0xF, 0xF, true);
    x += __int_as_float(t);
    t = __builtin_amdgcn_update_dpp(0, __float_as_int(x), 0x140, 0xF, 0xF, true);
    x += __int_as_float(t);
    return x;
}

// ---------------- kernel 1: s_nbr[b,j] = f·w_nbr, s_asp[b,j] = f·w_asp ----
__global__ __launch_bounds__(256) void k_proj(const float* __restrict__ feat,
                                              const float* __restrict__ watt,
                                              float* __restrict__ snbr,
                                              float* __restrict__ sasp)
{
    int flat = blockIdx.x * 4 + (threadIdx.x >> 6);   // b*N + j
    int lane = threadIdx.x & 63;
    const float* frow = feat + (size_t)flat * DD + lane * 4;
    const float* wn   = watt + lane * 4;              // w_nbr = w[:768]
    const float* wa   = watt + DD + DEPD + lane * 4;  // w_asp = w[832:1600]
    float accn = 0.f, acca = 0.f;
#pragma unroll
    for (int k = 0; k < 3; ++k) {
        float4 f = *(const float4*)(frow + k * 256);
        float4 n = *(const float4*)(wn + k * 256);
        float4 a = *(const float4*)(wa + k * 256);
        accn += f.x*n.x + f.y*n.y + f.z*n.z + f.w*n.w;
        acca += f.x*a.x + f.y*a.y + f.z*a.z + f.w*a.w;
    }
#pragma unroll
    for (int off = 1; off < 64; off <<= 1) {
        accn += __shfl_xor(accn, off);
        acca += __shfl_xor(acca, off);
    }
    if (lane == 0) { snbr[flat] = accn; sasp[flat] = acca; }
}

// ---------------- kernel 1b: featT[b][d][j] = bf16(feat[b][j][d]) ---------
__global__ __launch_bounds__(256) void k_cast(const float* __restrict__ feat,
                                              unsigned short* __restrict__ featT)
{
    int b  = blockIdx.z;
    int j0 = blockIdx.y * 64;
    int d0 = blockIdx.x * 64;
    int t  = threadIdx.x;

    __shared__ unsigned short lt[64][65];

    int dd = t & 63, j4 = t >> 6;
#pragma unroll
    for (int it = 0; it < 16; ++it) {
        int jj = j4 * 16 + it;
        float v = feat[((size_t)(b * NN) + (j0 + jj)) * DD + d0 + dd];
        lt[dd][jj] = to_bf16(v);
    }
    __syncthreads();

    int jj2 = t & 63, d4 = t >> 6;
#pragma unroll
    for (int it = 0; it < 16; ++it) {
        int dd2 = d4 * 16 + it;
        featT[((size_t)(b * DD) + (d0 + dd2)) * NN + j0 + jj2] = lt[dd2][jj2];
    }
}

// ---------------- kernel 2: sdep + masked softmax -> bf16 weights ---------
// R6/R8 body; ONLY change: the 4 __shfl_xor (ds_swizzle, LDS pipe) in the
// streaming loop replaced by dpp_sum16 (VALU pipe) -> no LDS-latency chain.
__global__ __launch_bounds__(256) void k_score(const float* __restrict__ adj,
                                               const float* __restrict__ snbr,
                                               const float* __restrict__ sasp,
                                               const int* __restrict__ aspect,
                                               const float* __restrict__ watt,
                                               unsigned short* __restrict__ wtsB,
                                               int* __restrict__ upd)
{
    int bi  = blockIdx.x;          // b*N + i
    int b   = bi >> 9;
    int tid = threadIdx.x;
    int g = tid >> 4, l = tid & 15;

    __shared__ float sdep[NN];     // -INF = masked
    __shared__ float sred[4];

    float4 wd = *(const float4*)(watt + DD + l * 4);   // w_dep = w[768:832]

    const float* arow = adj + (size_t)bi * NN * DEPD;
#pragma unroll 4
    for (int it = 0; it < NN / 16; ++it) {
        int j = it * 16 + g;
        float4 a = *(const float4*)(arow + (size_t)j * DEPD + l * 4);
        float p  = a.x*wd.x + a.y*wd.y + a.z*wd.z + a.w*wd.w;
        int   nz = (a.x != 0.f) | (a.y != 0.f) | (a.z != 0.f) | (a.w != 0.f);
        unsigned long long bal = __ballot(nz);
        unsigned int gnz = (unsigned int)((bal >> ((g & 3) * 16)) & 0xFFFFull);
        p = dpp_sum16(p);                              // VALU-only 16-lane sum
        if (l == 0) sdep[j] = gnz ? p : -INFINITY;
    }
    __syncthreads();

    float sa = sasp[bi];
    int j0 = tid, j1 = tid + 256;
    float d0 = sdep[j0], d1 = sdep[j1];
    float sc0 = d0 + snbr[(b << 9) + j0] + sa;   // -INF stays -INF
    float sc1 = d1 + snbr[(b << 9) + j1] + sa;

    float v = fmaxf(sc0, sc1);
#pragma unroll
    for (int off = 1; off < 64; off <<= 1) v = fmaxf(v, __shfl_xor(v, off));
    if ((tid & 63) == 0) sred[tid >> 6] = v;
    __syncthreads();
    float mx = fmaxf(fmaxf(sred[0], sred[1]), fmaxf(sred[2], sred[3]));
    __syncthreads();

    float e0 = d0 > -1e37f ? __expf(sc0 - mx) : 0.f;
    float e1 = d1 > -1e37f ? __expf(sc1 - mx) : 0.f;
    v = e0 + e1;
#pragma unroll
    for (int off = 1; off < 64; off <<= 1) v += __shfl_xor(v, off);
    if ((tid & 63) == 0) sred[tid >> 6] = v;
    __syncthreads();
    float sm = sred[0] + sred[1] + sred[2] + sred[3];

    float inv = sm > 0.f ? 1.f / sm : 0.f;
    size_t wb = (size_t)bi * NN;
    wtsB[wb + j0] = to_bf16(e0 * inv);     // coalesced 2B stores
    wtsB[wb + j1] = to_bf16(e1 * inv);
    if (tid == 0) upd[bi] = (aspect[bi] != 0) && (mx > -1e37f);
}

// ---------------- kernel 3: MFMA agg, XCD-pinned by batch ------------------
// (verbatim R8)
__global__ __launch_bounds__(256) void k_agg(const unsigned short* __restrict__ wtsB,
                                             const unsigned short* __restrict__ featT,
                                             const float* __restrict__ feat,
                                             const int* __restrict__ upd,
                                             float* __restrict__ out)
{
    int blk  = blockIdx.x;
    int b    = blk & 7;            // XCD pin
    int rem  = blk >> 3;           // 0..383
    int dblk = rem % 24;
    int iblk = rem / 24;           // 0..15

    int wave = threadIdx.x >> 6;
    int l    = threadIdx.x & 63;
    int i0   = iblk * 32 + (wave >> 1) * 16;
    int d0   = dblk * 32 + (wave & 1) * 16;
    int lr   = l & 15, lg = l >> 4;

    const unsigned short* wrow = wtsB  + ((size_t)(b * NN + i0 + lr)) * NN + lg * 8;
    const unsigned short* frow = featT + ((size_t)(b * DD + d0 + lr)) * NN + lg * 8;

    f32x4 acc = {0.f, 0.f, 0.f, 0.f};
#pragma unroll
    for (int k = 0; k < NN; k += 32) {
        bf16x8 av = *(const bf16x8*)(wrow + k);
        bf16x8 bv = *(const bf16x8*)(frow + k);
        acc = __builtin_amdgcn_mfma_f32_16x16x32_bf16(av, bv, acc, 0, 0, 0);
    }

    int dcol = d0 + lr;
#pragma unroll
    for (int reg = 0; reg < 4; ++reg) {
        int ii   = i0 + lg * 4 + reg;
        int rowi = b * NN + ii;
        float o  = upd[rowi] ? acc[reg] : feat[(size_t)rowi * DD + dcol];
        out[(size_t)rowi * DD + dcol] = o;
    }
}

extern "C" void kernel_launch(void* const* d_in, const int* in_sizes, int n_in,
                              void* d_out, int out_size, void* d_ws, size_t ws_size,
                              hipStream_t stream)
{
    (void)in_sizes; (void)n_in; (void)out_size; (void)ws_size;
    const float* feat = (const float*)d_in[0];
    const int*   asp  = (const int*)d_in[1];
    const float* adj  = (const float*)d_in[2];
    const float* watt = (const float*)d_in[3];
    float* out = (float*)d_out;

    // workspace: wtsB bf16 [8][512][512] (4MB) | featT bf16 [8][768][512]
    // (6.3MB) | snbr | sasp | upd
    unsigned short* wtsB  = (unsigned short*)d_ws;
    unsigned short* featT = wtsB + (size_t)BB * NN * NN;
    float* snbr = (float*)(featT + (size_t)BB * DD * NN);
    float* sasp = snbr + BB * NN;
    int*   upd  = (int*)(sasp + BB * NN);

    k_proj<<<BB * NN / 4, 256, 0, stream>>>(feat, watt, snbr, sasp);
    dim3 gc(DD / 64, NN / 64, BB);
    k_cast<<<gc, 256, 0, stream>>>(feat, featT);
    k_score<<<BB * NN, 256, 0, stream>>>(adj, snbr, sasp, asp, watt, wtsB, upd);
    k_agg<<<BB * (NN / 32) * (DD / 32), 256, 0, stream>>>(wtsB, featT, feat, upd, out);
}